// Round 21
// baseline (5925.367 us; speedup 1.0000x reference)
//
#include <hip/hip_runtime.h>
#include <cstdint>
#include <cstddef>

#define N_NODES 50000
#define N_EDGES 800000
#define F_IN_D 100
#define HDIM 128
#define CDIM 10
#define NSLAB 8
#define SLABN (N_NODES / NSLAB)        // 6250 src rows/slab; bf16 row 256B -> 1.6 MB slab
#define NKEY (NSLAB * N_NODES)         // 400000 (slab,dest) bins
#define NCH ((N_NODES + 255) / 256)    // 196
#define NCH2 ((NKEY + 255) / 256)      // 1563
#define NLINES 64
#define NBC 52                         // nodes per LDS chunk: 52*128*4 = 26.6 KB

typedef unsigned short ushortT;

__device__ __forceinline__ float bf2f(unsigned int b16) {
  return __uint_as_float(b16 << 16);
}
__device__ __forceinline__ unsigned int f2bf(float f) {   // RNE bf16
  unsigned int u = __float_as_uint(f);
  unsigned int r = u + 0x7FFFu + ((u >> 16) & 1u);
  return r >> 16;
}

struct Args {
  const float* x; const int* ei; const float* ew;
  const float* W1; const float* b1;
  const float* W2; const float* b2;
  const float* W3; const float* b3;
  float* out;
  ushortT* Yall;                       // bf16 [N][768]
  char* A; char* B;                    // bf16 [N][128] ping-pong (fp32 [N][64] ybuf / z in layer 3)
  ushortT* C; ushortT* D;              // h1, h2 (bf16 [N][128])
  int* ptrA; int* pos; int* srcs; float* wsrt;        // dest-major CSC (hop10)
  int* ptr2; int* pos2; int* srcs2; float* wsrt2;     // (slab,dest)-major CSC (hop128)
  int* row32; int* col32; float* deg; float* dis; int* cnt; int* part;
  int* cnt2; int* part2;
  int* lines; int* gbl;
};

// ---- grid barrier (R15-proven two-level arrival, ACQUIRE poll) ----
__device__ __forceinline__ void gbar(int* lines, int* gbl, int round, int gdim) {
  __syncthreads();
  if (threadIdx.x == 0) {
    __threadfence();
    const int perLine = gdim / NLINES;
    int old = atomicAdd(&lines[(blockIdx.x & (NLINES - 1)) * 32], 1);
    if (old == round * perLine - 1) atomicAdd(gbl, 1);
    while (__hip_atomic_load(gbl, __ATOMIC_ACQUIRE, __HIP_MEMORY_SCOPE_AGENT) < round * NLINES)
      __builtin_amdgcn_s_sleep(8);
    __threadfence();
  }
  __syncthreads();
}

// ---- GEMM tile (pointer-based shared arrays) ----
template <int K_DIM, int BMODE, bool XBF, bool OUTBF>
__device__ __forceinline__ void gemm_tile(const void* __restrict__ Xv, const float* __restrict__ W,
                                          const float* __restrict__ bias, bool addb,
                                          void* __restrict__ outv, int ostride, int tile,
                                          float (*xt)[68], float (*bt)[64]) {
  const int tid = threadIdx.x;
  const int tx = tid & 15;
  const int ty = tid >> 4;
  int n0, c0;
  if (BMODE == 0) { n0 = (tile >> 1) * 64; c0 = (tile & 1) * 64; }
  else            { n0 = tile * 64;        c0 = 0; }
  float acc[4][4];
#pragma unroll
  for (int i = 0; i < 4; ++i)
#pragma unroll
    for (int j = 0; j < 4; ++j) acc[i][j] = 0.f;

  for (int k0 = 0; k0 < K_DIM; k0 += 32) {
#pragma unroll
    for (int i = 0; i < 8; ++i) {
      int idx = tid + i * 256;
      int nl = idx >> 5, kl = idx & 31;
      int nn = n0 + nl, kg = k0 + kl;
      float v = 0.f;
      if (nn < N_NODES && kg < K_DIM) {
        if (XBF) v = bf2f(((const ushortT*)Xv)[(size_t)nn * K_DIM + kg]);
        else     v = ((const float*)Xv)[(size_t)nn * K_DIM + kg];
      }
      xt[kl][nl] = v;
    }
#pragma unroll
    for (int i = 0; i < 8; ++i) {
      int idx = tid + i * 256;
      int kl = idx >> 6, cl = idx & 63;
      int kg = k0 + kl;
      float v = 0.f;
      if (BMODE == 0) {
        if (kg < K_DIM) v = W[(size_t)kg * 128 + c0 + cl];
      } else {
        if (kg < K_DIM && cl < 6 * CDIM)
          v = W[(size_t)(cl / CDIM) * (K_DIM * CDIM) + (size_t)kg * CDIM + (cl % CDIM)];
      }
      bt[kl][cl] = v;
    }
    __syncthreads();
#pragma unroll
    for (int kk = 0; kk < 32; ++kk) {
      float4 xv = *(const float4*)&xt[kk][tx * 4];
      float4 bv = *(const float4*)&bt[kk][ty * 4];
      acc[0][0] += xv.x * bv.x; acc[0][1] += xv.x * bv.y; acc[0][2] += xv.x * bv.z; acc[0][3] += xv.x * bv.w;
      acc[1][0] += xv.y * bv.x; acc[1][1] += xv.y * bv.y; acc[1][2] += xv.y * bv.z; acc[1][3] += xv.y * bv.w;
      acc[2][0] += xv.z * bv.x; acc[2][1] += xv.z * bv.y; acc[2][2] += xv.z * bv.z; acc[2][3] += xv.z * bv.w;
      acc[3][0] += xv.w * bv.x; acc[3][1] += xv.w * bv.y; acc[3][2] += xv.w * bv.z; acc[3][3] += xv.w * bv.w;
    }
    __syncthreads();
  }
#pragma unroll
  for (int i = 0; i < 4; ++i) {
    int nn = n0 + tx * 4 + i;
    if (nn >= N_NODES) continue;
#pragma unroll
    for (int j = 0; j < 4; ++j) {
      int c = c0 + ty * 4 + j;
      if (addb) {
        if (BMODE == 0) acc[i][j] += bias[c];
        else if (c < CDIM) acc[i][j] += bias[c];
      }
    }
    if (OUTBF) {
      uint2 o;
      o.x = f2bf(acc[i][0]) | (f2bf(acc[i][1]) << 16);
      o.y = f2bf(acc[i][2]) | (f2bf(acc[i][3]) << 16);
      *(uint2*)&((ushortT*)outv)[(size_t)nn * ostride + c0 + ty * 4] = o;
    } else {
#pragma unroll
      for (int j = 0; j < 4; ++j)
        ((float*)outv)[(size_t)nn * ostride + c0 + ty * 4 + j] = acc[i][j];
    }
  }
}

// ---- slab-phased bf16 hop d=128 with LDS fp32 accumulators, chunked ----
// Block owns [n0,n1), processed in chunks of <= NBC nodes. Within a chunk:
// init acc from Y; 8 slab passes (pass p gathers only from src slab p,
// 1.6 MB -> per-XCD L2-resident; edges ordered by key = slab(src)*N + dest);
// finalize to bf16. Node n handled by half-wave (n - chunk0) % 8 throughout.
template <bool ELU>
__device__ __forceinline__ void hops5_phase(const uint2* __restrict__ P2, int pstr, int pOff,
                                            const uint2* __restrict__ Y2, int ystr, int yOff,
                                            const int* __restrict__ ptr2, const int* __restrict__ srcs2,
                                            const float* __restrict__ w2, uint2* __restrict__ Q2,
                                            float (*acc)[128], int n0, int n1) {
  const int hw = threadIdx.x >> 5;
  const int f4 = threadIdx.x & 31;
  const int fb = f4 * 4;
  for (int c0n = n0; c0n < n1; c0n += NBC) {
    const int c1n = (c0n + NBC < n1) ? c0n + NBC : n1;
    // init
    for (int n = c0n + hw; n < c1n; n += 8) {
      uint2 yv = Y2[(size_t)n * ystr + yOff + f4];
      int li = n - c0n;
      acc[li][fb + 0] = bf2f(yv.x & 0xFFFFu);
      acc[li][fb + 1] = bf2f(yv.x >> 16);
      acc[li][fb + 2] = bf2f(yv.y & 0xFFFFu);
      acc[li][fb + 3] = bf2f(yv.y >> 16);
    }
    // 8 slab passes
    for (int p = 0; p < NSLAB; ++p) {
      const int keyBase = p * N_NODES;
      for (int n = c0n + hw; n < c1n; n += 8) {
        const int b = ptr2[keyBase + n], e = ptr2[keyBase + n + 1];
        if (b == e) continue;
        const int li = n - c0n;
        float a0 = acc[li][fb + 0], a1 = acc[li][fb + 1];
        float a2 = acc[li][fb + 2], a3 = acc[li][fb + 3];
        int j = b;
        for (; j + 3 < e; j += 4) {
          int s0 = srcs2[j], s1 = srcs2[j + 1], s2 = srcs2[j + 2], s3 = srcs2[j + 3];
          float w0 = w2[j], w1 = w2[j + 1], w2v = w2[j + 2], w3 = w2[j + 3];
          uint2 v0 = P2[(size_t)s0 * pstr + pOff + f4];
          uint2 v1 = P2[(size_t)s1 * pstr + pOff + f4];
          uint2 v2 = P2[(size_t)s2 * pstr + pOff + f4];
          uint2 v3 = P2[(size_t)s3 * pstr + pOff + f4];
          a0 += w0 * bf2f(v0.x & 0xFFFFu) + w1 * bf2f(v1.x & 0xFFFFu)
              + w2v * bf2f(v2.x & 0xFFFFu) + w3 * bf2f(v3.x & 0xFFFFu);
          a1 += w0 * bf2f(v0.x >> 16) + w1 * bf2f(v1.x >> 16)
              + w2v * bf2f(v2.x >> 16) + w3 * bf2f(v3.x >> 16);
          a2 += w0 * bf2f(v0.y & 0xFFFFu) + w1 * bf2f(v1.y & 0xFFFFu)
              + w2v * bf2f(v2.y & 0xFFFFu) + w3 * bf2f(v3.y & 0xFFFFu);
          a3 += w0 * bf2f(v0.y >> 16) + w1 * bf2f(v1.y >> 16)
              + w2v * bf2f(v2.y >> 16) + w3 * bf2f(v3.y >> 16);
        }
        for (; j < e; ++j) {
          float w0 = w2[j];
          uint2 v0 = P2[(size_t)srcs2[j] * pstr + pOff + f4];
          a0 += w0 * bf2f(v0.x & 0xFFFFu);
          a1 += w0 * bf2f(v0.x >> 16);
          a2 += w0 * bf2f(v0.y & 0xFFFFu);
          a3 += w0 * bf2f(v0.y >> 16);
        }
        acc[li][fb + 0] = a0; acc[li][fb + 1] = a1;
        acc[li][fb + 2] = a2; acc[li][fb + 3] = a3;
      }
    }
    // finalize
    for (int n = c0n + hw; n < c1n; n += 8) {
      int li = n - c0n;
      float a0 = acc[li][fb + 0], a1 = acc[li][fb + 1];
      float a2 = acc[li][fb + 2], a3 = acc[li][fb + 3];
      if (ELU) {
        a0 = a0 > 0.f ? a0 : expm1f(a0);
        a1 = a1 > 0.f ? a1 : expm1f(a1);
        a2 = a2 > 0.f ? a2 : expm1f(a2);
        a3 = a3 > 0.f ? a3 : expm1f(a3);
      }
      uint2 o;
      o.x = f2bf(a0) | (f2bf(a1) << 16);
      o.y = f2bf(a2) | (f2bf(a3) << 16);
      Q2[(size_t)n * 32 + f4] = o;
    }
  }
}

// ---- hop d=10 (fp32, dest-major CSC) ----
__device__ __forceinline__ void hop10_phase(const float* __restrict__ z, int zStride, int zOff,
                                            const float* __restrict__ ybuf, int yOff,
                                            const int* __restrict__ ptr, const int* __restrict__ srcs,
                                            const float* __restrict__ wsrt, float* __restrict__ outp) {
  const int lane = threadIdx.x & 63;
  const int wid = threadIdx.x >> 6;
  const int sub = lane >> 4;
  const int f = lane & 15;
  for (int node = blockIdx.x * 4 + wid; node < N_NODES; node += gridDim.x * 4) {
    const int b = ptr[node], e = ptr[node + 1];
    const int len = e - b;
    const int js = b + (len * sub) / 4;
    const int je = b + (len * (sub + 1)) / 4;
    float acc = 0.f;
    if (f < CDIM) {
      if (sub == 0) acc = ybuf[(size_t)node * 64 + yOff + f];
      int j = js;
      for (; j + 1 < je; j += 2) {
        int s0 = srcs[j], s1 = srcs[j + 1];
        float w0 = wsrt[j], w1 = wsrt[j + 1];
        acc += w0 * z[(size_t)s0 * zStride + zOff + f] + w1 * z[(size_t)s1 * zStride + zOff + f];
      }
      if (j < je) acc += wsrt[j] * z[(size_t)srcs[j] * zStride + zOff + f];
    }
    acc += __shfl_xor(acc, 16);
    acc += __shfl_xor(acc, 32);
    if (sub == 0 && f < CDIM) outp[(size_t)node * CDIM + f] = acc;
  }
}

// in-place exclusive scan of nb partials (chunked, carry), total -> tot[totIdx]
__device__ __forceinline__ void scan_partials(int* partial, int nb, int* tot, int totIdx, int* sdi) {
  const int tid = threadIdx.x;
  int carry = 0;
  for (int base = 0; base < nb; base += 256) {
    int i = base + tid;
    int v = (i < nb) ? partial[i] : 0;
    sdi[tid] = v;
    __syncthreads();
    for (int o = 1; o < 256; o <<= 1) {
      int t2 = (tid >= o) ? sdi[tid - o] : 0;
      __syncthreads();
      sdi[tid] += t2;
      __syncthreads();
    }
    if (i < nb) partial[i] = carry + sdi[tid] - v;
    carry += sdi[255];
    __syncthreads();
  }
  if (tid == 0) tot[totIdx] = carry;
}

// ================= persistent kernel =================
__global__ __launch_bounds__(256, 4) void mega_kernel(Args a) {
  __shared__ float smemf[NBC * 128];              // 26.6 KB: acc | (xt,bt) | sdi (disjoint phases)
  float (*xt)[68] = (float(*)[68])smemf;
  float (*bt)[64] = (float(*)[64])(smemf + 32 * 68);
  int* sdi = (int*)smemf;
  float (*accL)[128] = (float(*)[128])smemf;
  const int tid = threadIdx.x;
  const int gtid = blockIdx.x * blockDim.x + tid;
  const int gstride = gridDim.x * blockDim.x;
  const int gdim = gridDim.x;
  const int TG0 = ((N_NODES + 63) / 64) * 2;      // 1564
  const int TG1 = (N_NODES + 63) / 64;            // 782
  const int NB = (N_NODES + gdim - 1) / gdim;
  const int n0 = blockIdx.x * NB;
  const int n1 = (n0 + NB < N_NODES) ? n0 + NB : N_NODES;
  int nb = 0;

  // P1: convert + degree/count atomics (both orderings), then layer-1 GEMM
  {
    bool is64 = true;
    for (int i = 0; i < 32; ++i) if (a.ei[2 * i + 1] != 0) is64 = false;
    for (int e = gtid; e < N_EDGES; e += gstride) {
      int r, c;
      if (is64) { r = a.ei[2 * e]; c = a.ei[2 * (N_EDGES + e)]; }
      else      { r = a.ei[e];     c = a.ei[N_EDGES + e]; }
      a.row32[e] = r; a.col32[e] = c;
      atomicAdd(&a.deg[c], a.ew[e]);
      atomicAdd(&a.cnt[c], 1);
      atomicAdd(&a.cnt2[(r / SLABN) * N_NODES + c], 1);
    }
  }
  for (int job = blockIdx.x; job < 6 * TG0; job += gdim) {
    int k = job / TG0, t = job % TG0;
    gemm_tile<F_IN_D, 0, false, true>(a.x, a.W1 + (size_t)k * F_IN_D * 128, a.b1, k == 0,
                                      a.Yall + k * 128, 768, t, xt, bt);
  }
  gbar(a.lines, a.gbl, ++nb, gdim);

  // P2: dis + chunk sums for cnt and cnt2
  for (int i = gtid; i < N_NODES; i += gstride) {
    float d = a.deg[i];
    a.dis[i] = d > 0.f ? rsqrtf(fmaxf(d, 1e-12f)) : 0.f;
  }
  for (int c = blockIdx.x; c < NCH; c += gdim) {
    int i = c * 256 + tid;
    sdi[tid] = (i < N_NODES) ? a.cnt[i] : 0;
    __syncthreads();
    for (int s = 128; s > 0; s >>= 1) { if (tid < s) sdi[tid] += sdi[tid + s]; __syncthreads(); }
    if (tid == 0) a.part[c] = sdi[0];
    __syncthreads();
  }
  for (int c = blockIdx.x; c < NCH2; c += gdim) {
    int i = c * 256 + tid;
    sdi[tid] = (i < NKEY) ? a.cnt2[i] : 0;
    __syncthreads();
    for (int s = 128; s > 0; s >>= 1) { if (tid < s) sdi[tid] += sdi[tid + s]; __syncthreads(); }
    if (tid == 0) a.part2[c] = sdi[0];
    __syncthreads();
  }
  gbar(a.lines, a.gbl, ++nb, gdim);

  // P3: block 0 scans part; block 1 scans part2
  if (blockIdx.x == 0) scan_partials(a.part, NCH, a.ptrA, N_NODES, sdi);
  if (blockIdx.x == 1) scan_partials(a.part2, NCH2, a.ptr2, NKEY, sdi);
  gbar(a.lines, a.gbl, ++nb, gdim);

  // P4: per-chunk exclusive scans -> (ptrA,pos) and (ptr2,pos2)
  for (int c = blockIdx.x; c < NCH; c += gdim) {
    int i = c * 256 + tid;
    int v = (i < N_NODES) ? a.cnt[i] : 0;
    sdi[tid] = v;
    __syncthreads();
    for (int o = 1; o < 256; o <<= 1) {
      int t2 = (tid >= o) ? sdi[tid - o] : 0;
      __syncthreads();
      sdi[tid] += t2;
      __syncthreads();
    }
    if (i < N_NODES) { int p = a.part[c] + sdi[tid] - v; a.ptrA[i] = p; a.pos[i] = p; }
    __syncthreads();
  }
  for (int c = blockIdx.x; c < NCH2; c += gdim) {
    int i = c * 256 + tid;
    int v = (i < NKEY) ? a.cnt2[i] : 0;
    sdi[tid] = v;
    __syncthreads();
    for (int o = 1; o < 256; o <<= 1) {
      int t2 = (tid >= o) ? sdi[tid - o] : 0;
      __syncthreads();
      sdi[tid] += t2;
      __syncthreads();
    }
    if (i < NKEY) { int p = a.part2[c] + sdi[tid] - v; a.ptr2[i] = p; a.pos2[i] = p; }
    __syncthreads();
  }
  gbar(a.lines, a.gbl, ++nb, gdim);

  // P5: place into both CSCs (+ fused norm)
  for (int e = gtid; e < N_EDGES; e += gstride) {
    int r = a.row32[e], c = a.col32[e];
    float nrm = a.dis[r] * a.ew[e] * a.dis[c];
    int slot = atomicAdd(&a.pos[c], 1);
    a.srcs[slot] = r;
    a.wsrt[slot] = nrm;
    int key = (r / SLABN) * N_NODES + c;
    int slot2 = atomicAdd(&a.pos2[key], 1);
    a.srcs2[slot2] = r;
    a.wsrt2[slot2] = nrm;
  }
  gbar(a.lines, a.gbl, ++nb, gdim);

  const uint2* Y2 = (const uint2*)a.Yall;         // stride 192 uint2; y_k at offset k*32
  uint2* A2 = (uint2*)a.A; uint2* B2 = (uint2*)a.B;
  uint2* C2 = (uint2*)a.C; uint2* D2 = (uint2*)a.D;

  // ===== layer 1 hops (slab-phased) =====
  hops5_phase<false>(Y2, 192, 5 * 32, Y2, 192, 4 * 32, a.ptr2, a.srcs2, a.wsrt2, A2, accL, n0, n1);
  gbar(a.lines, a.gbl, ++nb, gdim);
  hops5_phase<false>(A2, 32, 0, Y2, 192, 3 * 32, a.ptr2, a.srcs2, a.wsrt2, B2, accL, n0, n1);
  gbar(a.lines, a.gbl, ++nb, gdim);
  hops5_phase<false>(B2, 32, 0, Y2, 192, 2 * 32, a.ptr2, a.srcs2, a.wsrt2, A2, accL, n0, n1);
  gbar(a.lines, a.gbl, ++nb, gdim);
  hops5_phase<false>(A2, 32, 0, Y2, 192, 1 * 32, a.ptr2, a.srcs2, a.wsrt2, B2, accL, n0, n1);
  gbar(a.lines, a.gbl, ++nb, gdim);
  hops5_phase<true>(B2, 32, 0, Y2, 192, 0, a.ptr2, a.srcs2, a.wsrt2, C2, accL, n0, n1);
  gbar(a.lines, a.gbl, ++nb, gdim);
  // h1 = C (bf16)

  // ===== layer 2: GEMM (X = C bf16) then hops =====
  for (int job = blockIdx.x; job < 6 * TG0; job += gdim) {
    int k = job / TG0, t = job % TG0;
    gemm_tile<HDIM, 0, true, true>(a.C, a.W2 + (size_t)k * HDIM * 128, a.b2, k == 0,
                                   a.Yall + k * 128, 768, t, xt, bt);
  }
  gbar(a.lines, a.gbl, ++nb, gdim);
  hops5_phase<false>(Y2, 192, 5 * 32, Y2, 192, 4 * 32, a.ptr2, a.srcs2, a.wsrt2, A2, accL, n0, n1);
  gbar(a.lines, a.gbl, ++nb, gdim);
  hops5_phase<false>(A2, 32, 0, Y2, 192, 3 * 32, a.ptr2, a.srcs2, a.wsrt2, B2, accL, n0, n1);
  gbar(a.lines, a.gbl, ++nb, gdim);
  hops5_phase<false>(B2, 32, 0, Y2, 192, 2 * 32, a.ptr2, a.srcs2, a.wsrt2, A2, accL, n0, n1);
  gbar(a.lines, a.gbl, ++nb, gdim);
  hops5_phase<false>(A2, 32, 0, Y2, 192, 1 * 32, a.ptr2, a.srcs2, a.wsrt2, B2, accL, n0, n1);
  gbar(a.lines, a.gbl, ++nb, gdim);
  hops5_phase<true>(B2, 32, 0, Y2, 192, 0, a.ptr2, a.srcs2, a.wsrt2, D2, accL, n0, n1);
  gbar(a.lines, a.gbl, ++nb, gdim);
  // h2 = D (bf16)

  // ===== layer 3: GEMM (X = D bf16 -> fp32 ybuf = A [N][64]) then hop10 chain =====
  float* ybuf = (float*)a.A;
  float* z0 = (float*)a.B;
  float* z1 = (float*)(a.B + (size_t)N_NODES * 16 * 4);
  for (int t = blockIdx.x; t < TG1; t += gdim)
    gemm_tile<HDIM, 1, true, false>(a.D, a.W3, a.b3, true, ybuf, 64, t, xt, bt);
  gbar(a.lines, a.gbl, ++nb, gdim);
  hop10_phase(ybuf, 64, 50, ybuf, 40, a.ptrA, a.srcs, a.wsrt, z0); gbar(a.lines, a.gbl, ++nb, gdim);
  hop10_phase(z0, 10, 0, ybuf, 30, a.ptrA, a.srcs, a.wsrt, z1); gbar(a.lines, a.gbl, ++nb, gdim);
  hop10_phase(z1, 10, 0, ybuf, 20, a.ptrA, a.srcs, a.wsrt, z0); gbar(a.lines, a.gbl, ++nb, gdim);
  hop10_phase(z0, 10, 0, ybuf, 10, a.ptrA, a.srcs, a.wsrt, z1); gbar(a.lines, a.gbl, ++nb, gdim);
  hop10_phase(z1, 10, 0, ybuf, 0, a.ptrA, a.srcs, a.wsrt, a.out);
}

// ---------------- host ----------------

extern "C" void kernel_launch(void* const* d_in, const int* in_sizes, int n_in,
                              void* d_out, int out_size, void* d_ws, size_t ws_size,
                              hipStream_t stream) {
  Args a;
  a.x  = (const float*)d_in[0];
  a.ei = (const int*)d_in[1];
  a.ew = (const float*)d_in[2];
  a.W1 = (const float*)d_in[3];
  a.b1 = (const float*)d_in[4];
  a.W2 = (const float*)d_in[5];
  a.b2 = (const float*)d_in[6];
  a.W3 = (const float*)d_in[7];
  a.b3 = (const float*)d_in[8];
  a.out = (float*)d_out;

  const int N = N_NODES, E = N_EDGES;
  char* base = (char*)d_ws;
  size_t off = 0;
  auto alloc = [&](size_t bytes) -> char* {
    char* p = base + off;
    off += (bytes + 255) & ~(size_t)255;
    return p;
  };
  a.Yall = (ushortT*)alloc((size_t)N * 768 * 2);   // 76.8 MB
  a.A = alloc((size_t)N * 256);
  a.B = alloc((size_t)N * 256);
  a.C = (ushortT*)alloc((size_t)N * 128 * 2);
  a.D = (ushortT*)alloc((size_t)N * 128 * 2);
  a.ptrA = (int*)alloc((size_t)(N + 1) * 4);
  a.pos  = (int*)alloc((size_t)N * 4);
  a.srcs = (int*)alloc((size_t)E * 4);
  a.wsrt = (float*)alloc((size_t)E * 4);
  a.ptr2 = (int*)alloc((size_t)(NKEY + 1) * 4);
  a.pos2 = (int*)alloc((size_t)NKEY * 4);
  a.srcs2 = (int*)alloc((size_t)E * 4);
  a.wsrt2 = (float*)alloc((size_t)E * 4);
  a.lines = (int*)alloc(NLINES * 32 * 4);
  a.gbl   = (int*)alloc(256);

  // prep transients overlay A (A first written by the first layer-1 hop, after P5)
  char* t = a.A;
  a.row32 = (int*)t;            t += (size_t)E * 4;
  a.col32 = (int*)t;            t += (size_t)E * 4;
  a.deg   = (float*)t;          t += (size_t)N * 4;
  a.dis   = (float*)t;          t += (size_t)N * 4;
  a.cnt   = (int*)t;            t += (size_t)N * 4;
  a.part  = (int*)t;            t += 2048 * 4;
  // cnt2/part2 overlay B (B first written by the second layer-1 hop)
  char* t2 = a.B;
  a.cnt2  = (int*)t2;           t2 += (size_t)NKEY * 4;
  a.part2 = (int*)t2;           t2 += 2048 * 4;

  hipMemsetAsync(a.lines, 0, NLINES * 32 * 4, stream);
  hipMemsetAsync(a.gbl, 0, 256, stream);
  hipMemsetAsync(a.deg, 0, (size_t)N * 4, stream);
  hipMemsetAsync(a.cnt, 0, (size_t)N * 4, stream);
  hipMemsetAsync(a.cnt2, 0, (size_t)NKEY * 4, stream);

  int occ = 0;
  hipOccupancyMaxActiveBlocksPerMultiprocessor(&occ, (const void*)mega_kernel, 256, 0);
  if (occ < 1) occ = 1;
  int grid = occ * 256;           // co-residency capacity; NEVER force above this
  if (grid > 1024) grid = 1024;
  grid &= ~(NLINES - 1);          // gdim % NLINES == 0 (occ*256 is always a multiple of 64)
  if (grid < NLINES) grid = NLINES;

  void* args[] = { &a };
  hipLaunchCooperativeKernel((const void*)mega_kernel, dim3(grid), dim3(256), args, 0, stream);

  (void)in_sizes; (void)n_in; (void)out_size; (void)ws_size;
}

// Round 22
// 3491.698 us; speedup vs baseline: 1.6970x; 1.6970x over previous
//
#include <hip/hip_runtime.h>
#include <cstdint>
#include <cstddef>

#define N_NODES 50000
#define N_EDGES 800000
#define F_IN_D 100
#define HDIM 128
#define CDIM 10
#define NCH ((N_NODES + 255) / 256)   // 196 scan chunks
#define NLINES 64                     // barrier arrival lines

typedef unsigned short ushortT;
typedef __attribute__((ext_vector_type(8))) short bf16x8;
typedef __attribute__((ext_vector_type(4))) float f32x4;

__device__ __forceinline__ float bf2f(unsigned int b16) {
  return __uint_as_float(b16 << 16);
}
__device__ __forceinline__ unsigned int f2bf(float f) {   // RNE bf16
  unsigned int u = __float_as_uint(f);
  unsigned int r = u + 0x7FFFu + ((u >> 16) & 1u);
  return r >> 16;
}

struct Args {
  const float* x; const int* ei; const float* ew;
  const float* W1; const float* b1;
  const float* W2; const float* b2;
  const float* W3; const float* b3;
  float* out;
  ushortT* Yall;                       // bf16 [N][768]
  char* A; char* B;                    // bf16 [N][128] ping-pong (fp32 [N][64] ybuf / z in layer 3)
  ushortT* C; ushortT* D;              // h1, h2 (bf16 [N][128])
  int* ptrA; int* pos; int* srcs; float* wsrt;
  int* row32; int* col32; float* deg; float* dis; int* cnt; int* part;
  int* lines; int* gbl;
};

// ---- grid barrier (R15-proven two-level arrival, ACQUIRE poll) ----
__device__ __forceinline__ void gbar(int* lines, int* gbl, int round, int gdim) {
  __syncthreads();
  if (threadIdx.x == 0) {
    __threadfence();
    const int perLine = gdim / NLINES;
    int old = atomicAdd(&lines[(blockIdx.x & (NLINES - 1)) * 32], 1);
    if (old == round * perLine - 1) atomicAdd(gbl, 1);
    while (__hip_atomic_load(gbl, __ATOMIC_ACQUIRE, __HIP_MEMORY_SCOPE_AGENT) < round * NLINES)
      __builtin_amdgcn_s_sleep(8);
    __threadfence();
  }
  __syncthreads();
}

// ---- MFMA GEMM tile: out[n0:+64, c0:+64] = X @ B (+bias if addb), bf16 inputs ----
// xb: [64][128] bf16 X-tile (row-major). wb: [64][128] bf16 W-tile (COL-major: wb[col][k]).
// K padded to 128 with zeros. 4 waves; wave wv owns rows wv*16..+16; 4 col-tiles of 16.
// Layouts (16x16x32 bf16): A row=l&15, k=(l>>4)*8+e; B col=l&15, k same; C col=l&15, row=(l>>4)*4+j.
template <int K_DIM, int BMODE, bool XBF, bool OUTBF>
__device__ __forceinline__ void gemm_tile(const void* __restrict__ Xv, const float* __restrict__ W,
                                          const float* __restrict__ bias, bool addb,
                                          void* __restrict__ outv, int ostride, int tile,
                                          ushortT* xb, ushortT* wb) {
  const int tid = threadIdx.x;
  int n0, c0;
  if (BMODE == 0) { n0 = (tile >> 1) * 64; c0 = (tile & 1) * 64; }
  else            { n0 = tile * 64;        c0 = 0; }

  // stage X -> xb[64][128] bf16 (zero-pad k >= K_DIM)
#pragma unroll
  for (int i = 0; i < 32; ++i) {
    int idx = tid + i * 256;
    int nl = idx >> 7, kl = idx & 127;
    int nn = n0 + nl;
    ushortT v = 0;
    if (nn < N_NODES && kl < K_DIM) {
      if (XBF) v = ((const ushortT*)Xv)[(size_t)nn * K_DIM + kl];
      else     v = (ushortT)f2bf(((const float*)Xv)[(size_t)nn * K_DIM + kl]);
    }
    xb[nl * 128 + kl] = v;
  }
  // stage W -> wb[col][k] bf16 (transposed; zero-pad k >= K_DIM, col >= valid)
#pragma unroll
  for (int i = 0; i < 32; ++i) {
    int idx = tid + i * 256;
    int kl = idx >> 6, cl = idx & 63;
    float v = 0.f;
    if (BMODE == 0) {
      if (kl < K_DIM) v = W[(size_t)kl * 128 + c0 + cl];
    } else {
      if (kl < K_DIM && cl < 6 * CDIM)
        v = W[(size_t)(cl / CDIM) * (K_DIM * CDIM) + (size_t)kl * CDIM + (cl % CDIM)];
    }
    wb[cl * 128 + kl] = (ushortT)f2bf(v);
  }
  __syncthreads();

  const int wv = tid >> 6;
  const int l = tid & 63;
  const int lr = l & 15;
  const int lk = (l >> 4) * 8;

  f32x4 acc0 = {0.f, 0.f, 0.f, 0.f}, acc1 = acc0, acc2 = acc0, acc3 = acc0;
#pragma unroll
  for (int kc = 0; kc < 128; kc += 32) {
    bf16x8 af = *(const bf16x8*)&xb[(wv * 16 + lr) * 128 + kc + lk];
    bf16x8 b0 = *(const bf16x8*)&wb[(0 + lr) * 128 + kc + lk];
    bf16x8 b1 = *(const bf16x8*)&wb[(16 + lr) * 128 + kc + lk];
    bf16x8 b2 = *(const bf16x8*)&wb[(32 + lr) * 128 + kc + lk];
    bf16x8 b3 = *(const bf16x8*)&wb[(48 + lr) * 128 + kc + lk];
    acc0 = __builtin_amdgcn_mfma_f32_16x16x32_bf16(af, b0, acc0, 0, 0, 0);
    acc1 = __builtin_amdgcn_mfma_f32_16x16x32_bf16(af, b1, acc1, 0, 0, 0);
    acc2 = __builtin_amdgcn_mfma_f32_16x16x32_bf16(af, b2, acc2, 0, 0, 0);
    acc3 = __builtin_amdgcn_mfma_f32_16x16x32_bf16(af, b3, acc3, 0, 0, 0);
  }
  __syncthreads();   // LDS reused by next tile / other phases

  // write out: row = n0 + wv*16 + (l>>4)*4 + j; col = c0 + ct*16 + lr
  const int rbase = n0 + wv * 16 + (l >> 4) * 4;
  const int NCOL = (BMODE == 0) ? 64 : 6 * CDIM;
#pragma unroll
  for (int ct = 0; ct < 4; ++ct) {
    f32x4 av = (ct == 0) ? acc0 : (ct == 1) ? acc1 : (ct == 2) ? acc2 : acc3;
    int cc = ct * 16 + lr;
    if (cc >= NCOL) continue;
    int gc = c0 + cc;
    float badd = 0.f;
    if (addb) {
      if (BMODE == 0) badd = bias[gc];
      else if (gc < CDIM) badd = bias[gc];
    }
#pragma unroll
    for (int j = 0; j < 4; ++j) {
      int rr = rbase + j;
      if (rr >= N_NODES) continue;
      float r = av[j] + badd;
      if (OUTBF) ((ushortT*)outv)[(size_t)rr * ostride + gc] = (ushortT)f2bf(r);
      else       ((float*)outv)[(size_t)rr * ostride + gc] = r;
    }
  }
}

// ---- bf16 hop d=128, half-wave per node, 8-deep gather pipeline (R16-proven) ----
template <bool ELU>
__device__ __forceinline__ void hopb_phase(const uint2* __restrict__ P2, int pstr,
                                           const uint2* __restrict__ Y2, int ystr,
                                           const int* __restrict__ ptr, const int* __restrict__ srcs,
                                           const float* __restrict__ w, uint2* __restrict__ Q2) {
  const int hw = threadIdx.x >> 5;
  const int f4 = threadIdx.x & 31;
  for (int node = blockIdx.x * 8 + hw; node < N_NODES; node += gridDim.x * 8) {
    const int b = ptr[node], e = ptr[node + 1];
    uint2 yv = Y2[(size_t)node * ystr + f4];
    float a0 = bf2f(yv.x & 0xFFFFu), a1 = bf2f(yv.x >> 16);
    float a2 = bf2f(yv.y & 0xFFFFu), a3 = bf2f(yv.y >> 16);
    int j = b;
    for (; j + 7 < e; j += 8) {
      int s0 = srcs[j], s1 = srcs[j + 1], s2 = srcs[j + 2], s3 = srcs[j + 3];
      int s4 = srcs[j + 4], s5 = srcs[j + 5], s6 = srcs[j + 6], s7 = srcs[j + 7];
      float w0 = w[j], w1 = w[j + 1], w2 = w[j + 2], w3 = w[j + 3];
      float w4 = w[j + 4], w5 = w[j + 5], w6 = w[j + 6], w7 = w[j + 7];
      uint2 v0 = P2[(size_t)s0 * pstr + f4];
      uint2 v1 = P2[(size_t)s1 * pstr + f4];
      uint2 v2 = P2[(size_t)s2 * pstr + f4];
      uint2 v3 = P2[(size_t)s3 * pstr + f4];
      uint2 v4 = P2[(size_t)s4 * pstr + f4];
      uint2 v5 = P2[(size_t)s5 * pstr + f4];
      uint2 v6 = P2[(size_t)s6 * pstr + f4];
      uint2 v7 = P2[(size_t)s7 * pstr + f4];
      a0 += w0 * bf2f(v0.x & 0xFFFFu) + w1 * bf2f(v1.x & 0xFFFFu) + w2 * bf2f(v2.x & 0xFFFFu) + w3 * bf2f(v3.x & 0xFFFFu)
          + w4 * bf2f(v4.x & 0xFFFFu) + w5 * bf2f(v5.x & 0xFFFFu) + w6 * bf2f(v6.x & 0xFFFFu) + w7 * bf2f(v7.x & 0xFFFFu);
      a1 += w0 * bf2f(v0.x >> 16) + w1 * bf2f(v1.x >> 16) + w2 * bf2f(v2.x >> 16) + w3 * bf2f(v3.x >> 16)
          + w4 * bf2f(v4.x >> 16) + w5 * bf2f(v5.x >> 16) + w6 * bf2f(v6.x >> 16) + w7 * bf2f(v7.x >> 16);
      a2 += w0 * bf2f(v0.y & 0xFFFFu) + w1 * bf2f(v1.y & 0xFFFFu) + w2 * bf2f(v2.y & 0xFFFFu) + w3 * bf2f(v3.y & 0xFFFFu)
          + w4 * bf2f(v4.y & 0xFFFFu) + w5 * bf2f(v5.y & 0xFFFFu) + w6 * bf2f(v6.y & 0xFFFFu) + w7 * bf2f(v7.y & 0xFFFFu);
      a3 += w0 * bf2f(v0.y >> 16) + w1 * bf2f(v1.y >> 16) + w2 * bf2f(v2.y >> 16) + w3 * bf2f(v3.y >> 16)
          + w4 * bf2f(v4.y >> 16) + w5 * bf2f(v5.y >> 16) + w6 * bf2f(v6.y >> 16) + w7 * bf2f(v7.y >> 16);
    }
    for (; j + 1 < e; j += 2) {
      int s0 = srcs[j], s1 = srcs[j + 1];
      float w0 = w[j], w1 = w[j + 1];
      uint2 v0 = P2[(size_t)s0 * pstr + f4];
      uint2 v1 = P2[(size_t)s1 * pstr + f4];
      a0 += w0 * bf2f(v0.x & 0xFFFFu) + w1 * bf2f(v1.x & 0xFFFFu);
      a1 += w0 * bf2f(v0.x >> 16)     + w1 * bf2f(v1.x >> 16);
      a2 += w0 * bf2f(v0.y & 0xFFFFu) + w1 * bf2f(v1.y & 0xFFFFu);
      a3 += w0 * bf2f(v0.y >> 16)     + w1 * bf2f(v1.y >> 16);
    }
    if (j < e) {
      float w0 = w[j];
      uint2 v0 = P2[(size_t)srcs[j] * pstr + f4];
      a0 += w0 * bf2f(v0.x & 0xFFFFu);
      a1 += w0 * bf2f(v0.x >> 16);
      a2 += w0 * bf2f(v0.y & 0xFFFFu);
      a3 += w0 * bf2f(v0.y >> 16);
    }
    if (ELU) {
      a0 = a0 > 0.f ? a0 : expm1f(a0);
      a1 = a1 > 0.f ? a1 : expm1f(a1);
      a2 = a2 > 0.f ? a2 : expm1f(a2);
      a3 = a3 > 0.f ? a3 : expm1f(a3);
    }
    uint2 o;
    o.x = f2bf(a0) | (f2bf(a1) << 16);
    o.y = f2bf(a2) | (f2bf(a3) << 16);
    Q2[(size_t)node * 32 + f4] = o;
  }
}

// ---- hop d=10 (fp32, unchanged) ----
__device__ __forceinline__ void hop10_phase(const float* __restrict__ z, int zStride, int zOff,
                                            const float* __restrict__ ybuf, int yOff,
                                            const int* __restrict__ ptr, const int* __restrict__ srcs,
                                            const float* __restrict__ wsrt, float* __restrict__ outp) {
  const int lane = threadIdx.x & 63;
  const int wid = threadIdx.x >> 6;
  const int sub = lane >> 4;
  const int f = lane & 15;
  for (int node = blockIdx.x * 4 + wid; node < N_NODES; node += gridDim.x * 4) {
    const int b = ptr[node], e = ptr[node + 1];
    const int len = e - b;
    const int js = b + (len * sub) / 4;
    const int je = b + (len * (sub + 1)) / 4;
    float acc = 0.f;
    if (f < CDIM) {
      if (sub == 0) acc = ybuf[(size_t)node * 64 + yOff + f];
      int j = js;
      for (; j + 1 < je; j += 2) {
        int s0 = srcs[j], s1 = srcs[j + 1];
        float w0 = wsrt[j], w1 = wsrt[j + 1];
        acc += w0 * z[(size_t)s0 * zStride + zOff + f] + w1 * z[(size_t)s1 * zStride + zOff + f];
      }
      if (j < je) acc += wsrt[j] * z[(size_t)srcs[j] * zStride + zOff + f];
    }
    acc += __shfl_xor(acc, 16);
    acc += __shfl_xor(acc, 32);
    if (sub == 0 && f < CDIM) outp[(size_t)node * CDIM + f] = acc;
  }
}

// ================= persistent kernel, 21 barriers, 4 blocks/CU =================
__global__ __launch_bounds__(256, 4) void mega_kernel(Args a) {
  __shared__ ushortT smem[16384];              // 32 KB: xb[64][128] | wb[64][128]; sdi aliases
  ushortT* xb = smem;
  ushortT* wb = smem + 64 * 128;
  int* sdi = (int*)smem;
  const int tid = threadIdx.x;
  const int gtid = blockIdx.x * blockDim.x + tid;
  const int gstride = gridDim.x * blockDim.x;
  const int gdim = gridDim.x;
  const int TG0 = ((N_NODES + 63) / 64) * 2;   // 1564
  const int TG1 = (N_NODES + 63) / 64;         // 782
  int nb = 0;

  // P1: convert edges + degree atomics, then layer-1 GEMM (MFMA, x fp32->bf16)
  {
    bool is64 = true;
    for (int i = 0; i < 32; ++i) if (a.ei[2 * i + 1] != 0) is64 = false;
    for (int e = gtid; e < N_EDGES; e += gstride) {
      int r, c;
      if (is64) { r = a.ei[2 * e]; c = a.ei[2 * (N_EDGES + e)]; }
      else      { r = a.ei[e];     c = a.ei[N_EDGES + e]; }
      a.row32[e] = r; a.col32[e] = c;
      atomicAdd(&a.deg[c], a.ew[e]);
      atomicAdd(&a.cnt[c], 1);
    }
  }
  __syncthreads();
  for (int job = blockIdx.x; job < 6 * TG0; job += gdim) {
    int k = job / TG0, t = job % TG0;
    gemm_tile<F_IN_D, 0, false, true>(a.x, a.W1 + (size_t)k * F_IN_D * 128, a.b1, k == 0,
                                      a.Yall + k * 128, 768, t, xb, wb);
  }
  gbar(a.lines, a.gbl, ++nb, gdim);

  // P2: dis + per-chunk count sums
  for (int i = gtid; i < N_NODES; i += gstride) {
    float d = a.deg[i];
    a.dis[i] = d > 0.f ? rsqrtf(fmaxf(d, 1e-12f)) : 0.f;
  }
  for (int c = blockIdx.x; c < NCH; c += gdim) {
    int i = c * 256 + tid;
    sdi[tid] = (i < N_NODES) ? a.cnt[i] : 0;
    __syncthreads();
    for (int s = 128; s > 0; s >>= 1) { if (tid < s) sdi[tid] += sdi[tid + s]; __syncthreads(); }
    if (tid == 0) a.part[c] = sdi[0];
    __syncthreads();
  }
  gbar(a.lines, a.gbl, ++nb, gdim);

  // P3: block 0 scans the 196 partials
  if (blockIdx.x == 0) {
    int v = (tid < NCH) ? a.part[tid] : 0;
    sdi[tid] = v;
    __syncthreads();
    for (int o = 1; o < 256; o <<= 1) {
      int t2 = (tid >= o) ? sdi[tid - o] : 0;
      __syncthreads();
      sdi[tid] += t2;
      __syncthreads();
    }
    if (tid < NCH) a.part[tid] = sdi[tid] - v;
    if (tid == 255) a.ptrA[N_NODES] = sdi[255];
  }
  gbar(a.lines, a.gbl, ++nb, gdim);

  // P4: per-chunk exclusive scan -> ptrA, pos
  for (int c = blockIdx.x; c < NCH; c += gdim) {
    int i = c * 256 + tid;
    int v = (i < N_NODES) ? a.cnt[i] : 0;
    sdi[tid] = v;
    __syncthreads();
    for (int o = 1; o < 256; o <<= 1) {
      int t2 = (tid >= o) ? sdi[tid - o] : 0;
      __syncthreads();
      sdi[tid] += t2;
      __syncthreads();
    }
    if (i < N_NODES) { int p = a.part[c] + sdi[tid] - v; a.ptrA[i] = p; a.pos[i] = p; }
    __syncthreads();
  }
  gbar(a.lines, a.gbl, ++nb, gdim);

  // P5: place into CSC + fused norm
  for (int e = gtid; e < N_EDGES; e += gstride) {
    int r = a.row32[e], c = a.col32[e];
    int slot = atomicAdd(&a.pos[c], 1);
    a.srcs[slot] = r;
    a.wsrt[slot] = a.dis[r] * a.ew[e] * a.dis[c];
  }
  gbar(a.lines, a.gbl, ++nb, gdim);

  const uint2* Y2 = (const uint2*)a.Yall;      // stride 192 uint2; y_k at offset k*32
  uint2* A2 = (uint2*)a.A; uint2* B2 = (uint2*)a.B;
  uint2* C2 = (uint2*)a.C; uint2* D2 = (uint2*)a.D;

  // ===== layer 1 hops =====
  hopb_phase<false>(Y2 + 5 * 32, 192, Y2 + 4 * 32, 192, a.ptrA, a.srcs, a.wsrt, A2);
  gbar(a.lines, a.gbl, ++nb, gdim);
  hopb_phase<false>(A2, 32, Y2 + 3 * 32, 192, a.ptrA, a.srcs, a.wsrt, B2);
  gbar(a.lines, a.gbl, ++nb, gdim);
  hopb_phase<false>(B2, 32, Y2 + 2 * 32, 192, a.ptrA, a.srcs, a.wsrt, A2);
  gbar(a.lines, a.gbl, ++nb, gdim);
  hopb_phase<false>(A2, 32, Y2 + 1 * 32, 192, a.ptrA, a.srcs, a.wsrt, B2);
  gbar(a.lines, a.gbl, ++nb, gdim);
  hopb_phase<true>(B2, 32, Y2 + 0 * 32, 192, a.ptrA, a.srcs, a.wsrt, C2);
  gbar(a.lines, a.gbl, ++nb, gdim);
  // h1 = C (bf16)

  // ===== layer 2: GEMM (X = C bf16, MFMA) then hops =====
  for (int job = blockIdx.x; job < 6 * TG0; job += gdim) {
    int k = job / TG0, t = job % TG0;
    gemm_tile<HDIM, 0, true, true>(a.C, a.W2 + (size_t)k * HDIM * 128, a.b2, k == 0,
                                   a.Yall + k * 128, 768, t, xb, wb);
  }
  gbar(a.lines, a.gbl, ++nb, gdim);
  hopb_phase<false>(Y2 + 5 * 32, 192, Y2 + 4 * 32, 192, a.ptrA, a.srcs, a.wsrt, A2);
  gbar(a.lines, a.gbl, ++nb, gdim);
  hopb_phase<false>(A2, 32, Y2 + 3 * 32, 192, a.ptrA, a.srcs, a.wsrt, B2);
  gbar(a.lines, a.gbl, ++nb, gdim);
  hopb_phase<false>(B2, 32, Y2 + 2 * 32, 192, a.ptrA, a.srcs, a.wsrt, A2);
  gbar(a.lines, a.gbl, ++nb, gdim);
  hopb_phase<false>(A2, 32, Y2 + 1 * 32, 192, a.ptrA, a.srcs, a.wsrt, B2);
  gbar(a.lines, a.gbl, ++nb, gdim);
  hopb_phase<true>(B2, 32, Y2 + 0 * 32, 192, a.ptrA, a.srcs, a.wsrt, D2);
  gbar(a.lines, a.gbl, ++nb, gdim);
  // h2 = D (bf16)

  // ===== layer 3: GEMM (X = D bf16, MFMA -> fp32 ybuf = A [N][64]) then hop10 chain =====
  float* ybuf = (float*)a.A;
  float* z0 = (float*)a.B;
  float* z1 = (float*)(a.B + (size_t)N_NODES * 16 * 4);
  for (int t = blockIdx.x; t < TG1; t += gdim)
    gemm_tile<HDIM, 1, true, false>(a.D, a.W3, a.b3, true, ybuf, 64, t, xb, wb);
  gbar(a.lines, a.gbl, ++nb, gdim);
  hop10_phase(ybuf, 64, 50, ybuf, 40, a.ptrA, a.srcs, a.wsrt, z0); gbar(a.lines, a.gbl, ++nb, gdim);
  hop10_phase(z0, 10, 0, ybuf, 30, a.ptrA, a.srcs, a.wsrt, z1); gbar(a.lines, a.gbl, ++nb, gdim);
  hop10_phase(z1, 10, 0, ybuf, 20, a.ptrA, a.srcs, a.wsrt, z0); gbar(a.lines, a.gbl, ++nb, gdim);
  hop10_phase(z0, 10, 0, ybuf, 10, a.ptrA, a.srcs, a.wsrt, z1); gbar(a.lines, a.gbl, ++nb, gdim);
  hop10_phase(z1, 10, 0, ybuf, 0, a.ptrA, a.srcs, a.wsrt, a.out);
}

// ---------------- host ----------------

extern "C" void kernel_launch(void* const* d_in, const int* in_sizes, int n_in,
                              void* d_out, int out_size, void* d_ws, size_t ws_size,
                              hipStream_t stream) {
  Args a;
  a.x  = (const float*)d_in[0];
  a.ei = (const int*)d_in[1];
  a.ew = (const float*)d_in[2];
  a.W1 = (const float*)d_in[3];
  a.b1 = (const float*)d_in[4];
  a.W2 = (const float*)d_in[5];
  a.b2 = (const float*)d_in[6];
  a.W3 = (const float*)d_in[7];
  a.b3 = (const float*)d_in[8];
  a.out = (float*)d_out;

  const int N = N_NODES, E = N_EDGES;
  char* base = (char*)d_ws;
  size_t off = 0;
  auto alloc = [&](size_t bytes) -> char* {
    char* p = base + off;
    off += (bytes + 255) & ~(size_t)255;
    return p;
  };
  a.Yall = (ushortT*)alloc((size_t)N * 768 * 2);   // 76.8 MB (bf16)
  a.A = alloc((size_t)N * 256);
  a.B = alloc((size_t)N * 256);
  a.C = (ushortT*)alloc((size_t)N * 128 * 2);
  a.D = (ushortT*)alloc((size_t)N * 128 * 2);
  a.ptrA = (int*)alloc((size_t)(N + 1) * 4);
  a.pos  = (int*)alloc((size_t)N * 4);
  a.srcs = (int*)alloc((size_t)E * 4);
  a.wsrt = (float*)alloc((size_t)E * 4);
  a.lines = (int*)alloc(NLINES * 32 * 4);
  a.gbl   = (int*)alloc(256);

  // prep transients overlay A (A first written by the first layer-1 hop, after P5).
  char* t = a.A;
  a.row32 = (int*)t;            t += (size_t)E * 4;
  a.col32 = (int*)t;            t += (size_t)E * 4;
  a.deg   = (float*)t;          t += (size_t)N * 4;
  a.dis   = (float*)t;          t += (size_t)N * 4;
  a.cnt   = (int*)t;            t += (size_t)N * 4;
  a.part  = (int*)t;            t += 2048 * 4;

  hipMemsetAsync(a.lines, 0, NLINES * 32 * 4, stream);
  hipMemsetAsync(a.gbl, 0, 256, stream);
  hipMemsetAsync(a.deg, 0, (size_t)N * 4, stream);
  hipMemsetAsync(a.cnt, 0, (size_t)N * 4, stream);

  int occ = 0;
  hipOccupancyMaxActiveBlocksPerMultiprocessor(&occ, (const void*)mega_kernel, 256, 0);
  if (occ < 1) occ = 1;
  int grid = occ * 256;
  if (grid > 1024) grid = 1024;
  grid &= ~(NLINES - 1);
  if (grid < NLINES) grid = NLINES;

  void* args[] = { &a };
  hipLaunchCooperativeKernel((const void*)mega_kernel, dim3(grid), dim3(256), args, 0, stream);

  (void)in_sizes; (void)n_in; (void)out_size; (void)ws_size;
}